// Round 3
// baseline (401.819 us; speedup 1.0000x reference)
//
#include <hip/hip_runtime.h>
#include <hip/hip_bf16.h>
#include <stdint.h>

// Problem constants: B=2, T=2048, D=1024, H=16, HD=64
#define B_  2
#define T_  2048
#define D_  1024
#define H_  16
#define HD_ 64

typedef __bf16 bf16x8 __attribute__((ext_vector_type(8)));
typedef __bf16 bf16x4 __attribute__((ext_vector_type(4)));
typedef float  f32x4  __attribute__((ext_vector_type(4)));

// ---------------------------------------------------------------------------
// Dtype detector + bias conversion. One block of 256 threads.
// Inspects x's first 8192 16-bit words:
//  - bf16 N(0,1) data: exponent field <= ~134, never >150; no exact zeros.
//  - fp32 data read as u16: even (low-mantissa) words have uniform exponent
//    field -> ~41% exceed 150.
//  - fp32 storage of bf16-rounded values: even words are all 0x0000.
// flag=1 -> inputs/outputs are fp32.  Also emits bo as canonical fp32.
// ---------------------------------------------------------------------------
__global__ void detect_kernel(const void* __restrict__ x_raw, const void* __restrict__ bo_raw,
                              int* __restrict__ flagp, float* __restrict__ bo_f) {
  __shared__ int sh[2];
  const int tid = threadIdx.x;
  if (tid == 0) { sh[0] = 0; sh[1] = 0; }
  __syncthreads();
  const unsigned short* xw = (const unsigned short*)x_raw;
  int h = 0, z = 0;
  for (int i = tid; i < 8192; i += 256) {
    const unsigned short wv = xw[i];
    const int e = (wv >> 7) & 0xFF;
    if (e > 150) ++h;
    if (((i & 1) == 0) && (wv == 0)) ++z;
  }
  atomicAdd(&sh[0], h);
  atomicAdd(&sh[1], z);
  __syncthreads();
  const int f32 = (sh[0] > 512 || sh[1] > 1024) ? 1 : 0;
  for (int i = tid; i < 1024; i += 256)
    bo_f[i] = f32 ? ((const float*)bo_raw)[i] : (float)((const __bf16*)bo_raw)[i];
  if (tid == 0) *flagp = f32;
}

// ---------------------------------------------------------------------------
// Canonicalize x -> bf16 (copy if already bf16, convert if fp32).
// Grid 4096 x 256, 4 elements/thread.
// ---------------------------------------------------------------------------
__global__ void convert_x_kernel(const void* __restrict__ x_raw, const int* __restrict__ flagp,
                                 __bf16* __restrict__ xc) {
  const int f32 = *flagp;
  const int i0 = (blockIdx.x * 256 + threadIdx.x) * 4;
  if (f32) {
    const float* xf = (const float*)x_raw;
#pragma unroll
    for (int k = 0; k < 4; ++k) xc[i0 + k] = (__bf16)xf[i0 + k];
  } else {
    *(bf16x4*)(xc + i0) = *(const bf16x4*)((const __bf16*)x_raw + i0);
  }
}

// ---------------------------------------------------------------------------
// Transpose the four 1024x1024 weight matrices (either dtype) to bf16:
// dst[n][k] = src[k][n].  wq,wk,wv -> wqkv_t rows [0,3072); wo -> wo_t.
// ---------------------------------------------------------------------------
__global__ void transpose_w_kernel(const void* __restrict__ wq, const void* __restrict__ wk,
                                   const void* __restrict__ wv, const void* __restrict__ wo,
                                   const int* __restrict__ flagp,
                                   __bf16* __restrict__ wqkv_t, __bf16* __restrict__ wo_t) {
  __shared__ __bf16 tile[32][33];
  const int f32 = *flagp;
  const int z = blockIdx.z;
  const void* src = (z == 0) ? wq : (z == 1) ? wk : (z == 2) ? wv : wo;
  __bf16* dst = (z < 3) ? (wqkv_t + (size_t)z * 1024 * 1024) : wo_t;
  const int n0 = blockIdx.x * 32, k0 = blockIdx.y * 32;
  const int tx = threadIdx.x, ty = threadIdx.y;
#pragma unroll
  for (int i = 0; i < 4; ++i) {
    const size_t idx = (size_t)(k0 + ty + 8 * i) * 1024 + n0 + tx;
    tile[ty + 8 * i][tx] = f32 ? (__bf16)((const float*)src)[idx] : ((const __bf16*)src)[idx];
  }
  __syncthreads();
#pragma unroll
  for (int i = 0; i < 4; ++i)
    dst[(size_t)(n0 + ty + 8 * i) * 1024 + k0 + tx] = tile[tx][ty + 8 * i];
}

// ---------------------------------------------------------------------------
// 128x128-tile bf16 MFMA GEMM, C = A[M][K] * Bt[N][K]^T, K=1024.
// 4 waves (2x2), each wave 64x64 via 4x4 frags of 16x16x32 MFMA. BK=64.
// Explicit staging (vector global load -> ds_write) into XOR-swizzled layout.
// MODE 0: epilogue scatters Q (x0.125) / K to [b,h,t,hd], V transposed to
//         [b,h,hd,t].   MODE 1: epilogue adds bias, stores bf16 or fp32.
// ---------------------------------------------------------------------------
template <int MODE>
__launch_bounds__(256)
__global__ void gemm128_kernel(const __bf16* __restrict__ A, const __bf16* __restrict__ Bt, int K,
                               __bf16* __restrict__ q_b, __bf16* __restrict__ k_b,
                               __bf16* __restrict__ vt_b,
                               const float* __restrict__ bo_f, const int* __restrict__ flagp,
                               void* __restrict__ outp) {
  __shared__ __bf16 As[128 * 64];
  __shared__ __bf16 Bs[128 * 64];
  const int tid  = threadIdx.x;
  const int w    = tid >> 6, lane = tid & 63;
  const int quad = lane >> 4, lr = lane & 15;
  const int tm = blockIdx.y * 128, tn = blockIdx.x * 128;
  const int wm = (w >> 1) * 64, wn = (w & 1) * 64;
  const int lrow   = lane >> 3;              // row within 8-row chunk (0..7)
  const int gchunk = (lane & 7) ^ lrow;      // swizzled global 16B k-group

  f32x4 acc[4][4] = {};

  for (int k0 = 0; k0 < K; k0 += 64) {
    bf16x8 ar[4], br[4];
#pragma unroll
    for (int c = 0; c < 4; ++c) {
      const int row = (w * 4 + c) * 8 + lrow;
      ar[c] = *(const bf16x8*)(A  + (size_t)(tm + row) * K + k0 + gchunk * 8);
      br[c] = *(const bf16x8*)(Bt + (size_t)(tn + row) * K + k0 + gchunk * 8);
    }
    __syncthreads();   // previous iteration's LDS reads complete
#pragma unroll
    for (int c = 0; c < 4; ++c) {
      const int chunk = w * 4 + c;
      *(bf16x8*)(As + chunk * 512 + lane * 8) = ar[c];
      *(bf16x8*)(Bs + chunk * 512 + lane * 8) = br[c];
    }
    __syncthreads();
#pragma unroll
    for (int ks = 0; ks < 2; ++ks) {
      bf16x8 af[4], bfr[4];
#pragma unroll
      for (int mi = 0; mi < 4; ++mi) {
        const int row = wm + mi * 16 + lr;
        const int ch  = (ks * 4 + quad) ^ (row & 7);
        af[mi] = *(const bf16x8*)(As + row * 64 + ch * 8);
      }
#pragma unroll
      for (int ni = 0; ni < 4; ++ni) {
        const int row = wn + ni * 16 + lr;
        const int ch  = (ks * 4 + quad) ^ (row & 7);
        bfr[ni] = *(const bf16x8*)(Bs + row * 64 + ch * 8);
      }
#pragma unroll
      for (int mi = 0; mi < 4; ++mi)
#pragma unroll
        for (int ni = 0; ni < 4; ++ni)
          acc[mi][ni] = __builtin_amdgcn_mfma_f32_16x16x32_bf16(af[mi], bfr[ni], acc[mi][ni], 0, 0, 0);
    }
  }

  // Epilogue. C mapping: row = quad*4 + reg, col = lr (within each 16x16 frag).
  if (MODE == 0) {
#pragma unroll
    for (int mi = 0; mi < 4; ++mi) {
      const int mrow0 = tm + wm + mi * 16 + quad * 4;
      const int b  = mrow0 >> 11;
      const int t0 = mrow0 & 2047;
#pragma unroll
      for (int ni = 0; ni < 4; ++ni) {
        const int ncol = tn + wn + ni * 16 + lr;
        const int mat  = ncol >> 10;        // 0=Q 1=K 2=V (wave-uniform)
        const int nn   = ncol & 1023;
        const int h = nn >> 6, hd = nn & 63;
        if (mat == 0) {
#pragma unroll
          for (int r = 0; r < 4; ++r)
            q_b[((size_t)((b * H_ + h) * T_ + t0 + r)) * HD_ + hd] =
                (__bf16)(acc[mi][ni][r] * 0.125f);   // pre-apply 1/sqrt(64)
        } else if (mat == 1) {
#pragma unroll
          for (int r = 0; r < 4; ++r)
            k_b[((size_t)((b * H_ + h) * T_ + t0 + r)) * HD_ + hd] =
                (__bf16)(acc[mi][ni][r]);
        } else {
          bf16x4 pk;
#pragma unroll
          for (int r = 0; r < 4; ++r) pk[r] = (__bf16)(acc[mi][ni][r]);
          *(bf16x4*)(vt_b + ((size_t)(b * H_ + h) * HD_ + hd) * T_ + t0) = pk;  // 8B store
        }
      }
    }
  } else {
    const int f32out = *flagp;
#pragma unroll
    for (int mi = 0; mi < 4; ++mi) {
      const int m0 = tm + wm + mi * 16 + quad * 4;
#pragma unroll
      for (int ni = 0; ni < 4; ++ni) {
        const int n = tn + wn + ni * 16 + lr;
        const float bias = bo_f[n];
#pragma unroll
        for (int r = 0; r < 4; ++r) {
          const float val = acc[mi][ni][r] + bias;
          if (f32out) ((float*)outp)[(size_t)(m0 + r) * D_ + n] = val;
          else        ((__bf16*)outp)[(size_t)(m0 + r) * D_ + n] = (__bf16)val;
        }
      }
    }
  }
}

// ---------------------------------------------------------------------------
// Flash attention (causal). Grid (T/64, B*H), block 256 = 4 waves.
// Wave w owns Q rows q0..q0+15 (q0 = 64*bx + 16*w). KV tiles of 64.
// Q pre-scaled by 1/8; V pre-transposed to [b,h,hd,t].
// Per-wave LDS region only; sP double-buffered across j-iterations.
// ---------------------------------------------------------------------------
__launch_bounds__(256)
__global__ void attn_kernel(const __bf16* __restrict__ q_b, const __bf16* __restrict__ k_b,
                            const __bf16* __restrict__ vt_b, __bf16* __restrict__ ctx) {
  __shared__ __bf16 sP[4][2][16][80];   // per-wave double-buffered P tile
  const int tid  = threadIdx.x;
  const int w    = tid >> 6, lane = tid & 63;
  const int quad = lane >> 4, lr = lane & 15;
  const int bh = blockIdx.y;
  const int q0 = blockIdx.x * 64 + w * 16;
  const __bf16* qh = q_b  + (size_t)bh * T_ * HD_;
  const __bf16* kh = k_b  + (size_t)bh * T_ * HD_;
  const __bf16* vh = vt_b + (size_t)bh * HD_ * T_;

  bf16x8 qf[2];
#pragma unroll
  for (int ks = 0; ks < 2; ++ks)
    qf[ks] = *(const bf16x8*)(qh + (size_t)(q0 + lr) * HD_ + ks * 32 + quad * 8);

  f32x4 o[4] = {};
  float m_run[4], l_run[4];
#pragma unroll
  for (int r = 0; r < 4; ++r) { m_run[r] = -3.0e38f; l_run[r] = 0.f; }

  for (int j0 = 0; j0 <= q0 + 15; j0 += 64) {
    const int pb = (j0 >> 6) & 1;
    // S = (Q/8) K^T for a 16x64 tile
    f32x4 s[4] = {};
#pragma unroll
    for (int ni = 0; ni < 4; ++ni)
#pragma unroll
      for (int ks = 0; ks < 2; ++ks) {
        bf16x8 kf = *(const bf16x8*)(kh + (size_t)(j0 + ni * 16 + lr) * HD_ + ks * 32 + quad * 8);
        s[ni] = __builtin_amdgcn_mfma_f32_16x16x32_bf16(qf[ks], kf, s[ni], 0, 0, 0);
      }
    // causal mask (only diagonal tiles need it)
    if (j0 + 63 > q0) {
#pragma unroll
      for (int ni = 0; ni < 4; ++ni) {
        const int col = j0 + ni * 16 + lr;
#pragma unroll
        for (int r = 0; r < 4; ++r) {
          const int row = q0 + quad * 4 + r;
          if (col > row) s[ni][r] = -3.0e38f;
        }
      }
    }
    // online softmax: each row's 64 cols live on the 16 lanes of one quad
    float mt[4];
#pragma unroll
    for (int r = 0; r < 4; ++r)
      mt[r] = fmaxf(fmaxf(s[0][r], s[1][r]), fmaxf(s[2][r], s[3][r]));
#pragma unroll
    for (int off = 1; off <= 8; off <<= 1)
#pragma unroll
      for (int r = 0; r < 4; ++r)
        mt[r] = fmaxf(mt[r], __shfl_xor(mt[r], off, 16));
    float alpha[4], rs[4];
#pragma unroll
    for (int r = 0; r < 4; ++r) {
      const float mn = fmaxf(m_run[r], mt[r]);
      alpha[r] = __expf(m_run[r] - mn);
      m_run[r] = mn;
      float sum = 0.f;
#pragma unroll
      for (int ni = 0; ni < 4; ++ni) {
        const float pv = __expf(s[ni][r] - mn);
        s[ni][r] = pv;
        sum += pv;
      }
      rs[r] = sum;
    }
#pragma unroll
    for (int off = 1; off <= 8; off <<= 1)
#pragma unroll
      for (int r = 0; r < 4; ++r)
        rs[r] += __shfl_xor(rs[r], off, 16);
#pragma unroll
    for (int r = 0; r < 4; ++r)
      l_run[r] = l_run[r] * alpha[r] + rs[r];
#pragma unroll
    for (int ni = 0; ni < 4; ++ni)
#pragma unroll
      for (int r = 0; r < 4; ++r)
        o[ni][r] *= alpha[r];
    // P (C-layout) -> LDS -> A-layout fragments
#pragma unroll
    for (int ni = 0; ni < 4; ++ni)
#pragma unroll
      for (int r = 0; r < 4; ++r)
        sP[w][pb][quad * 4 + r][ni * 16 + lr] = (__bf16)s[ni][r];
    asm volatile("s_waitcnt lgkmcnt(0)" ::: "memory");
    bf16x8 pf[2];
#pragma unroll
    for (int ks = 0; ks < 2; ++ks)
      pf[ks] = *(const bf16x8*)(&sP[w][pb][lr][ks * 32 + quad * 8]);
    // O += P * V  (B-operand from transposed V: contiguous 16B)
#pragma unroll
    for (int ni = 0; ni < 4; ++ni)
#pragma unroll
      for (int ks = 0; ks < 2; ++ks) {
        bf16x8 vf = *(const bf16x8*)(vh + (size_t)(ni * 16 + lr) * T_ + j0 + ks * 32 + quad * 8);
        o[ni] = __builtin_amdgcn_mfma_f32_16x16x32_bf16(pf[ks], vf, o[ni], 0, 0, 0);
      }
  }
  // normalize and store ctx in merged [b*T+t][h*64+d] layout (bf16)
  const int b = bh >> 4, h = bh & 15;
#pragma unroll
  for (int ni = 0; ni < 4; ++ni)
#pragma unroll
    for (int r = 0; r < 4; ++r) {
      const int t = q0 + quad * 4 + r;
      ctx[((size_t)(b * T_ + t)) * D_ + h * HD_ + ni * 16 + lr] =
          (__bf16)(o[ni][r] / l_run[r]);
    }
}

// ---------------------------------------------------------------------------
extern "C" void kernel_launch(void* const* d_in, const int* in_sizes, int n_in,
                              void* d_out, int out_size, void* d_ws, size_t ws_size,
                              hipStream_t stream) {
  (void)in_sizes; (void)n_in; (void)out_size; (void)ws_size;
  const void* x  = d_in[0];
  const void* wq = d_in[1];
  const void* wk = d_in[2];
  const void* wv = d_in[3];
  const void* wo = d_in[4];
  const void* bo = d_in[5];

  // Workspace layout (~42 MB). ctx overlaps wqkv_t (dead after gemm<0>).
  char* ws = (char*)d_ws;
  __bf16* ctx    = (__bf16*)(ws + 0);           // [4096][1024] = 8 MB
  __bf16* wqkv_t = (__bf16*)(ws + 0);           // 3072x1024 = 6 MB (dead after gemm<0>)
  __bf16* wo_t   = (__bf16*)(ws + 8388608);     // 1024x1024 = 2 MB
  __bf16* q_b    = (__bf16*)(ws + 10485760);    // [2][16][2048][64] = 8 MB
  __bf16* k_b    = (__bf16*)(ws + 18874368);    // 8 MB
  __bf16* vt_b   = (__bf16*)(ws + 27262976);    // [2][16][64][2048] = 8 MB
  __bf16* xc     = (__bf16*)(ws + 35651584);    // canonical bf16 x = 8 MB
  float*  bo_f   = (float*) (ws + 44040192);    // 4 KB
  int*    flagp  = (int*)   (ws + 44044288);    // 4 B

  detect_kernel<<<1, 256, 0, stream>>>(x, bo, flagp, bo_f);
  convert_x_kernel<<<4096, 256, 0, stream>>>(x, flagp, xc);
  transpose_w_kernel<<<dim3(32, 32, 4), dim3(32, 8, 1), 0, stream>>>(wq, wk, wv, wo, flagp, wqkv_t, wo_t);
  gemm128_kernel<0><<<dim3(24, 32), 256, 0, stream>>>(xc, wqkv_t, 1024, q_b, k_b, vt_b, nullptr, flagp, nullptr);
  attn_kernel<<<dim3(32, 32), 256, 0, stream>>>(q_b, k_b, vt_b, ctx);
  gemm128_kernel<1><<<dim3(8, 32), 256, 0, stream>>>(ctx, wo_t, 1024, nullptr, nullptr, nullptr, bo_f, flagp, d_out);
}

// Round 4
// 223.614 us; speedup vs baseline: 1.7969x; 1.7969x over previous
//
#include <hip/hip_runtime.h>
#include <hip/hip_bf16.h>
#include <stdint.h>

// Problem constants: B=2, T=2048, D=1024, H=16, HD=64
#define B_  2
#define T_  2048
#define D_  1024
#define H_  16
#define HD_ 64

typedef __bf16 bf16x8 __attribute__((ext_vector_type(8)));
typedef __bf16 bf16x4 __attribute__((ext_vector_type(4)));
typedef float  f32x4  __attribute__((ext_vector_type(4)));

// ---------------------------------------------------------------------------
// Dtype detector + bias conversion. One block of 256 threads.  (validated R3)
// flag=1 -> inputs/outputs are fp32.  Also emits bo as canonical fp32.
// ---------------------------------------------------------------------------
__global__ void detect_kernel(const void* __restrict__ x_raw, const void* __restrict__ bo_raw,
                              int* __restrict__ flagp, float* __restrict__ bo_f) {
  __shared__ int sh[2];
  const int tid = threadIdx.x;
  if (tid == 0) { sh[0] = 0; sh[1] = 0; }
  __syncthreads();
  const unsigned short* xw = (const unsigned short*)x_raw;
  int h = 0, z = 0;
  for (int i = tid; i < 8192; i += 256) {
    const unsigned short wv = xw[i];
    const int e = (wv >> 7) & 0xFF;
    if (e > 150) ++h;
    if (((i & 1) == 0) && (wv == 0)) ++z;
  }
  atomicAdd(&sh[0], h);
  atomicAdd(&sh[1], z);
  __syncthreads();
  const int f32 = (sh[0] > 512 || sh[1] > 1024) ? 1 : 0;
  for (int i = tid; i < 1024; i += 256)
    bo_f[i] = f32 ? ((const float*)bo_raw)[i] : (float)((const __bf16*)bo_raw)[i];
  if (tid == 0) *flagp = f32;
}

// ---------------------------------------------------------------------------
// Canonicalize x -> bf16. Grid 4096 x 256, 4 elements/thread.   (validated R3)
// ---------------------------------------------------------------------------
__global__ void convert_x_kernel(const void* __restrict__ x_raw, const int* __restrict__ flagp,
                                 __bf16* __restrict__ xc) {
  const int f32 = *flagp;
  const int i0 = (blockIdx.x * 256 + threadIdx.x) * 4;
  if (f32) {
    const float* xf = (const float*)x_raw;
#pragma unroll
    for (int k = 0; k < 4; ++k) xc[i0 + k] = (__bf16)xf[i0 + k];
  } else {
    *(bf16x4*)(xc + i0) = *(const bf16x4*)((const __bf16*)x_raw + i0);
  }
}

// ---------------------------------------------------------------------------
// Transpose weights (either dtype) to bf16: dst[n][k] = src[k][n]. (validated R3)
// ---------------------------------------------------------------------------
__global__ void transpose_w_kernel(const void* __restrict__ wq, const void* __restrict__ wk,
                                   const void* __restrict__ wv, const void* __restrict__ wo,
                                   const int* __restrict__ flagp,
                                   __bf16* __restrict__ wqkv_t, __bf16* __restrict__ wo_t) {
  __shared__ __bf16 tile[32][33];
  const int f32 = *flagp;
  const int z = blockIdx.z;
  const void* src = (z == 0) ? wq : (z == 1) ? wk : (z == 2) ? wv : wo;
  __bf16* dst = (z < 3) ? (wqkv_t + (size_t)z * 1024 * 1024) : wo_t;
  const int n0 = blockIdx.x * 32, k0 = blockIdx.y * 32;
  const int tx = threadIdx.x, ty = threadIdx.y;
#pragma unroll
  for (int i = 0; i < 4; ++i) {
    const size_t idx = (size_t)(k0 + ty + 8 * i) * 1024 + n0 + tx;
    tile[ty + 8 * i][tx] = f32 ? (__bf16)((const float*)src)[idx] : ((const __bf16*)src)[idx];
  }
  __syncthreads();
#pragma unroll
  for (int i = 0; i < 4; ++i)
    dst[(size_t)(n0 + ty + 8 * i) * 1024 + k0 + tx] = tile[tx][ty + 8 * i];
}

// ---------------------------------------------------------------------------
// 128x128-tile bf16 MFMA GEMM (validated R3, unchanged).
// ---------------------------------------------------------------------------
template <int MODE>
__launch_bounds__(256)
__global__ void gemm128_kernel(const __bf16* __restrict__ A, const __bf16* __restrict__ Bt, int K,
                               __bf16* __restrict__ q_b, __bf16* __restrict__ k_b,
                               __bf16* __restrict__ vt_b,
                               const float* __restrict__ bo_f, const int* __restrict__ flagp,
                               void* __restrict__ outp) {
  __shared__ __bf16 As[128 * 64];
  __shared__ __bf16 Bs[128 * 64];
  const int tid  = threadIdx.x;
  const int w    = tid >> 6, lane = tid & 63;
  const int quad = lane >> 4, lr = lane & 15;
  const int tm = blockIdx.y * 128, tn = blockIdx.x * 128;
  const int wm = (w >> 1) * 64, wn = (w & 1) * 64;
  const int lrow   = lane >> 3;
  const int gchunk = (lane & 7) ^ lrow;

  f32x4 acc[4][4] = {};

  for (int k0 = 0; k0 < K; k0 += 64) {
    bf16x8 ar[4], br[4];
#pragma unroll
    for (int c = 0; c < 4; ++c) {
      const int row = (w * 4 + c) * 8 + lrow;
      ar[c] = *(const bf16x8*)(A  + (size_t)(tm + row) * K + k0 + gchunk * 8);
      br[c] = *(const bf16x8*)(Bt + (size_t)(tn + row) * K + k0 + gchunk * 8);
    }
    __syncthreads();
#pragma unroll
    for (int c = 0; c < 4; ++c) {
      const int chunk = w * 4 + c;
      *(bf16x8*)(As + chunk * 512 + lane * 8) = ar[c];
      *(bf16x8*)(Bs + chunk * 512 + lane * 8) = br[c];
    }
    __syncthreads();
#pragma unroll
    for (int ks = 0; ks < 2; ++ks) {
      bf16x8 af[4], bfr[4];
#pragma unroll
      for (int mi = 0; mi < 4; ++mi) {
        const int row = wm + mi * 16 + lr;
        const int ch  = (ks * 4 + quad) ^ (row & 7);
        af[mi] = *(const bf16x8*)(As + row * 64 + ch * 8);
      }
#pragma unroll
      for (int ni = 0; ni < 4; ++ni) {
        const int row = wn + ni * 16 + lr;
        const int ch  = (ks * 4 + quad) ^ (row & 7);
        bfr[ni] = *(const bf16x8*)(Bs + row * 64 + ch * 8);
      }
#pragma unroll
      for (int mi = 0; mi < 4; ++mi)
#pragma unroll
        for (int ni = 0; ni < 4; ++ni)
          acc[mi][ni] = __builtin_amdgcn_mfma_f32_16x16x32_bf16(af[mi], bfr[ni], acc[mi][ni], 0, 0, 0);
    }
  }

  if (MODE == 0) {
#pragma unroll
    for (int mi = 0; mi < 4; ++mi) {
      const int mrow0 = tm + wm + mi * 16 + quad * 4;
      const int b  = mrow0 >> 11;
      const int t0 = mrow0 & 2047;
#pragma unroll
      for (int ni = 0; ni < 4; ++ni) {
        const int ncol = tn + wn + ni * 16 + lr;
        const int mat  = ncol >> 10;
        const int nn   = ncol & 1023;
        const int h = nn >> 6, hd = nn & 63;
        if (mat == 0) {
#pragma unroll
          for (int r = 0; r < 4; ++r)
            q_b[((size_t)((b * H_ + h) * T_ + t0 + r)) * HD_ + hd] =
                (__bf16)(acc[mi][ni][r] * 0.125f);
        } else if (mat == 1) {
#pragma unroll
          for (int r = 0; r < 4; ++r)
            k_b[((size_t)((b * H_ + h) * T_ + t0 + r)) * HD_ + hd] =
                (__bf16)(acc[mi][ni][r]);
        } else {
          bf16x4 pk;
#pragma unroll
          for (int r = 0; r < 4; ++r) pk[r] = (__bf16)(acc[mi][ni][r]);
          *(bf16x4*)(vt_b + ((size_t)(b * H_ + h) * HD_ + hd) * T_ + t0) = pk;
        }
      }
    }
  } else {
    const int f32out = *flagp;
#pragma unroll
    for (int mi = 0; mi < 4; ++mi) {
      const int m0 = tm + wm + mi * 16 + quad * 4;
#pragma unroll
      for (int ni = 0; ni < 4; ++ni) {
        const int n = tn + wn + ni * 16 + lr;
        const float bias = bo_f[n];
#pragma unroll
        for (int r = 0; r < 4; ++r) {
          const float val = acc[mi][ni][r] + bias;
          if (f32out) ((float*)outp)[(size_t)(m0 + r) * D_ + n] = val;
          else        ((__bf16*)outp)[(size_t)(m0 + r) * D_ + n] = (__bf16)val;
        }
      }
    }
  }
}

// ---------------------------------------------------------------------------
// Flash attention v2 (causal). Grid (16, B*H), block 256 = 4 waves.
// Block bx processes Q-tile pair (bx, 31-bx): 33 j-iterations total per block
// -> perfectly uniform work across all 512 blocks (fixes CU imbalance).
// K and V^T tiles staged ONCE per block into XOR-swizzled LDS (4x less global
// traffic); register prefetch of tile j+1 overlaps compute of tile j.
// Unified trip count across waves (causal mask covers sub-diagonal rows), so
// __syncthreads is legal.
// ---------------------------------------------------------------------------
__launch_bounds__(256)
__global__ void attn_kernel(const __bf16* __restrict__ q_b, const __bf16* __restrict__ k_b,
                            const __bf16* __restrict__ vt_b, __bf16* __restrict__ ctx) {
  __shared__ __bf16 sK[64 * 64];          // 8 KB, XOR-swizzled 16B chunks
  __shared__ __bf16 sV[64 * 64];          // 8 KB, rows = hd, cols = kv
  __shared__ __bf16 sP[4][2][16][80];     // per-wave double-buffered P tile
  const int tid  = threadIdx.x;
  const int w    = tid >> 6, lane = tid & 63;
  const int quad = lane >> 4, lr = lane & 15;
  const int bh = blockIdx.y;
  const int bx = blockIdx.x;
  const __bf16* qh = q_b  + (size_t)bh * T_ * HD_;
  const __bf16* kh = k_b  + (size_t)bh * T_ * HD_;
  const __bf16* vh = vt_b + (size_t)bh * HD_ * T_;
  const int b = bh >> 4, h = bh & 15;

  // staging geometry: 512 16B chunks per 64x64 tile; 2 chunks/thread
  const int r0 = tid >> 3, r1 = (tid + 256) >> 3;   // rows (0..63)
  const int g0 = tid & 7,  g1 = tid & 7;            // chunk-in-row

#pragma unroll
  for (int half = 0; half < 2; ++half) {
    const int tq = half ? (31 - bx) : bx;
    const int q0 = tq * 64 + w * 16;
    const int nj = tq + 1;

    bf16x8 qf[2];
#pragma unroll
    for (int ks = 0; ks < 2; ++ks)
      qf[ks] = *(const bf16x8*)(qh + (size_t)(q0 + lr) * HD_ + ks * 32 + quad * 8);

    f32x4 o[4] = {};
    float m_run[4], l_run[4];
#pragma unroll
    for (int r = 0; r < 4; ++r) { m_run[r] = -3.0e38f; l_run[r] = 0.f; }

    // prefetch tile j=0 into registers
    bf16x8 kr0 = *(const bf16x8*)(kh + (size_t)r0 * HD_ + g0 * 8);
    bf16x8 kr1 = *(const bf16x8*)(kh + (size_t)r1 * HD_ + g1 * 8);
    bf16x8 vr0 = *(const bf16x8*)(vh + (size_t)r0 * T_ + g0 * 8);
    bf16x8 vr1 = *(const bf16x8*)(vh + (size_t)r1 * T_ + g1 * 8);

    for (int j = 0; j < nj; ++j) {
      const int j0 = j * 64;
      const int pb = j & 1;
      __syncthreads();   // all waves done reading sK/sV from previous iter
      *(bf16x8*)(sK + r0 * 64 + (g0 ^ (r0 & 7)) * 8) = kr0;
      *(bf16x8*)(sK + r1 * 64 + (g1 ^ (r1 & 7)) * 8) = kr1;
      *(bf16x8*)(sV + r0 * 64 + (g0 ^ (r0 & 7)) * 8) = vr0;
      *(bf16x8*)(sV + r1 * 64 + (g1 ^ (r1 & 7)) * 8) = vr1;
      __syncthreads();
      if (j + 1 < nj) {   // overlap next-tile global loads with compute
        const int jn = j0 + 64;
        kr0 = *(const bf16x8*)(kh + (size_t)(jn + r0) * HD_ + g0 * 8);
        kr1 = *(const bf16x8*)(kh + (size_t)(jn + r1) * HD_ + g1 * 8);
        vr0 = *(const bf16x8*)(vh + (size_t)r0 * T_ + jn + g0 * 8);
        vr1 = *(const bf16x8*)(vh + (size_t)r1 * T_ + jn + g1 * 8);
      }
      // S = (Q/8) K^T for this wave's 16x64 stripe (K from LDS)
      f32x4 s[4] = {};
#pragma unroll
      for (int ni = 0; ni < 4; ++ni) {
        const int row = ni * 16 + lr;
#pragma unroll
        for (int ks = 0; ks < 2; ++ks) {
          const int ch = (ks * 4 + quad) ^ (row & 7);
          bf16x8 kf = *(const bf16x8*)(sK + row * 64 + ch * 8);
          s[ni] = __builtin_amdgcn_mfma_f32_16x16x32_bf16(qf[ks], kf, s[ni], 0, 0, 0);
        }
      }
      // causal mask on diagonal tile (unified trip count: always check last j)
      if (j0 + 63 > q0) {
#pragma unroll
        for (int ni = 0; ni < 4; ++ni) {
          const int col = j0 + ni * 16 + lr;
#pragma unroll
          for (int r = 0; r < 4; ++r) {
            const int row = q0 + quad * 4 + r;
            if (col > row) s[ni][r] = -3.0e38f;
          }
        }
      }
      // online softmax (rows on the 16 lanes of each quad)
      float mt[4];
#pragma unroll
      for (int r = 0; r < 4; ++r)
        mt[r] = fmaxf(fmaxf(s[0][r], s[1][r]), fmaxf(s[2][r], s[3][r]));
#pragma unroll
      for (int off = 1; off <= 8; off <<= 1)
#pragma unroll
        for (int r = 0; r < 4; ++r)
          mt[r] = fmaxf(mt[r], __shfl_xor(mt[r], off, 16));
      float alpha[4], rs[4];
#pragma unroll
      for (int r = 0; r < 4; ++r) {
        const float mn = fmaxf(m_run[r], mt[r]);
        alpha[r] = __expf(m_run[r] - mn);
        m_run[r] = mn;
        float sum = 0.f;
#pragma unroll
        for (int ni = 0; ni < 4; ++ni) {
          const float pv = __expf(s[ni][r] - mn);
          s[ni][r] = pv;
          sum += pv;
        }
        rs[r] = sum;
      }
#pragma unroll
      for (int off = 1; off <= 8; off <<= 1)
#pragma unroll
        for (int r = 0; r < 4; ++r)
          rs[r] += __shfl_xor(rs[r], off, 16);
#pragma unroll
      for (int r = 0; r < 4; ++r)
        l_run[r] = l_run[r] * alpha[r] + rs[r];
#pragma unroll
      for (int ni = 0; ni < 4; ++ni)
#pragma unroll
        for (int r = 0; r < 4; ++r)
          o[ni][r] *= alpha[r];
      // P (C-layout) -> LDS -> A-layout fragments (per-wave region, no barrier)
#pragma unroll
      for (int ni = 0; ni < 4; ++ni)
#pragma unroll
        for (int r = 0; r < 4; ++r)
          sP[w][pb][quad * 4 + r][ni * 16 + lr] = (__bf16)s[ni][r];
      asm volatile("s_waitcnt lgkmcnt(0)" ::: "memory");
      bf16x8 pf[2];
#pragma unroll
      for (int ks = 0; ks < 2; ++ks)
        pf[ks] = *(const bf16x8*)(&sP[w][pb][lr][ks * 32 + quad * 8]);
      // O += P * V  (V^T from LDS: row = hd, cols = kv)
#pragma unroll
      for (int ni = 0; ni < 4; ++ni) {
        const int row = ni * 16 + lr;
#pragma unroll
        for (int ks = 0; ks < 2; ++ks) {
          const int ch = (ks * 4 + quad) ^ (row & 7);
          bf16x8 vf = *(const bf16x8*)(sV + row * 64 + ch * 8);
          o[ni] = __builtin_amdgcn_mfma_f32_16x16x32_bf16(pf[ks], vf, o[ni], 0, 0, 0);
        }
      }
    }
    // normalize and store ctx in merged [b*T+t][h*64+d] layout (bf16)
#pragma unroll
    for (int ni = 0; ni < 4; ++ni)
#pragma unroll
      for (int r = 0; r < 4; ++r) {
        const int t = q0 + quad * 4 + r;
        ctx[((size_t)(b * T_ + t)) * D_ + h * HD_ + ni * 16 + lr] =
            (__bf16)(o[ni][r] / l_run[r]);
      }
  }
}

// ---------------------------------------------------------------------------
extern "C" void kernel_launch(void* const* d_in, const int* in_sizes, int n_in,
                              void* d_out, int out_size, void* d_ws, size_t ws_size,
                              hipStream_t stream) {
  (void)in_sizes; (void)n_in; (void)out_size; (void)ws_size;
  const void* x  = d_in[0];
  const void* wq = d_in[1];
  const void* wk = d_in[2];
  const void* wv = d_in[3];
  const void* wo = d_in[4];
  const void* bo = d_in[5];

  char* ws = (char*)d_ws;
  __bf16* ctx    = (__bf16*)(ws + 0);           // [4096][1024] = 8 MB
  __bf16* wqkv_t = (__bf16*)(ws + 0);           // 3072x1024 = 6 MB (dead after gemm<0>)
  __bf16* wo_t   = (__bf16*)(ws + 8388608);     // 1024x1024 = 2 MB
  __bf16* q_b    = (__bf16*)(ws + 10485760);    // [2][16][2048][64] = 8 MB
  __bf16* k_b    = (__bf16*)(ws + 18874368);    // 8 MB
  __bf16* vt_b   = (__bf16*)(ws + 27262976);    // [2][16][64][2048] = 8 MB
  __bf16* xc     = (__bf16*)(ws + 35651584);    // canonical bf16 x = 8 MB
  float*  bo_f   = (float*) (ws + 44040192);    // 4 KB
  int*    flagp  = (int*)   (ws + 44044288);    // 4 B

  detect_kernel<<<1, 256, 0, stream>>>(x, bo, flagp, bo_f);
  convert_x_kernel<<<4096, 256, 0, stream>>>(x, flagp, xc);
  transpose_w_kernel<<<dim3(32, 32, 4), dim3(32, 8, 1), 0, stream>>>(wq, wk, wv, wo, flagp, wqkv_t, wo_t);
  gemm128_kernel<0><<<dim3(24, 32), 256, 0, stream>>>(xc, wqkv_t, 1024, q_b, k_b, vt_b, nullptr, flagp, nullptr);
  attn_kernel<<<dim3(16, 32), 256, 0, stream>>>(q_b, k_b, vt_b, ctx);
  gemm128_kernel<1><<<dim3(8, 32), 256, 0, stream>>>(ctx, wo_t, 1024, nullptr, nullptr, nullptr, bo_f, flagp, d_out);
}

// Round 5
// 214.712 us; speedup vs baseline: 1.8714x; 1.0415x over previous
//
#include <hip/hip_runtime.h>
#include <hip/hip_bf16.h>
#include <stdint.h>

// Problem constants: B=2, T=2048, D=1024, H=16, HD=64
#define B_  2
#define T_  2048
#define D_  1024
#define H_  16
#define HD_ 64

typedef __bf16 bf16x8 __attribute__((ext_vector_type(8)));
typedef __bf16 bf16x4 __attribute__((ext_vector_type(4)));
typedef float  f32x4  __attribute__((ext_vector_type(4)));

__device__ __forceinline__ void async_copy16(const void* g, void* l) {
  __builtin_amdgcn_global_load_lds((__attribute__((address_space(1))) void*)(g),
                                   (__attribute__((address_space(3))) void*)(l),
                                   16, 0, 0);
}

// ---------------------------------------------------------------------------
// Dtype detector + bias conversion. One block of 256 threads.  (validated R3)
// flag=1 -> inputs/outputs are fp32.  Also emits bo as canonical fp32.
// ---------------------------------------------------------------------------
__global__ void detect_kernel(const void* __restrict__ x_raw, const void* __restrict__ bo_raw,
                              int* __restrict__ flagp, float* __restrict__ bo_f) {
  __shared__ int sh[2];
  const int tid = threadIdx.x;
  if (tid == 0) { sh[0] = 0; sh[1] = 0; }
  __syncthreads();
  const unsigned short* xw = (const unsigned short*)x_raw;
  int h = 0, z = 0;
  for (int i = tid; i < 8192; i += 256) {
    const unsigned short wv = xw[i];
    const int e = (wv >> 7) & 0xFF;
    if (e > 150) ++h;
    if (((i & 1) == 0) && (wv == 0)) ++z;
  }
  atomicAdd(&sh[0], h);
  atomicAdd(&sh[1], z);
  __syncthreads();
  const int f32 = (sh[0] > 512 || sh[1] > 1024) ? 1 : 0;
  for (int i = tid; i < 1024; i += 256)
    bo_f[i] = f32 ? ((const float*)bo_raw)[i] : (float)((const __bf16*)bo_raw)[i];
  if (tid == 0) *flagp = f32;
}

// ---------------------------------------------------------------------------
// Canonicalize x -> bf16. Grid 4096 x 256, 4 elements/thread.   (validated R3)
// ---------------------------------------------------------------------------
__global__ void convert_x_kernel(const void* __restrict__ x_raw, const int* __restrict__ flagp,
                                 __bf16* __restrict__ xc) {
  const int f32 = *flagp;
  const int i0 = (blockIdx.x * 256 + threadIdx.x) * 4;
  if (f32) {
    const float* xf = (const float*)x_raw;
#pragma unroll
    for (int k = 0; k < 4; ++k) xc[i0 + k] = (__bf16)xf[i0 + k];
  } else {
    *(bf16x4*)(xc + i0) = *(const bf16x4*)((const __bf16*)x_raw + i0);
  }
}

// ---------------------------------------------------------------------------
// Transpose weights (either dtype) to bf16: dst[n][k] = src[k][n]. (validated R3)
// ---------------------------------------------------------------------------
__global__ void transpose_w_kernel(const void* __restrict__ wq, const void* __restrict__ wk,
                                   const void* __restrict__ wv, const void* __restrict__ wo,
                                   const int* __restrict__ flagp,
                                   __bf16* __restrict__ wqkv_t, __bf16* __restrict__ wo_t) {
  __shared__ __bf16 tile[32][33];
  const int f32 = *flagp;
  const int z = blockIdx.z;
  const void* src = (z == 0) ? wq : (z == 1) ? wk : (z == 2) ? wv : wo;
  __bf16* dst = (z < 3) ? (wqkv_t + (size_t)z * 1024 * 1024) : wo_t;
  const int n0 = blockIdx.x * 32, k0 = blockIdx.y * 32;
  const int tx = threadIdx.x, ty = threadIdx.y;
#pragma unroll
  for (int i = 0; i < 4; ++i) {
    const size_t idx = (size_t)(k0 + ty + 8 * i) * 1024 + n0 + tx;
    tile[ty + 8 * i][tx] = f32 ? (__bf16)((const float*)src)[idx] : ((const __bf16*)src)[idx];
  }
  __syncthreads();
#pragma unroll
  for (int i = 0; i < 4; ++i)
    dst[(size_t)(n0 + ty + 8 * i) * 1024 + k0 + tx] = tile[tx][ty + 8 * i];
}

// ---------------------------------------------------------------------------
// 128x128-tile bf16 MFMA GEMM, C = A[M][K] * Bt[N][K]^T.
// R5: staging via global_load_lds width=16 (m97 ladder step). LDS layout is
// byte-identical to the R3/R4-validated explicit-staging layout:
// lane l of chunk-instr writes base+l*16B = row chunk*8+(l>>3), group
// (l&7)^(l>>3) -> slot(row,g) = row*64 + (g^(row&7))*8, which the reader uses.
// ---------------------------------------------------------------------------
template <int MODE>
__launch_bounds__(256)
__global__ void gemm128_kernel(const __bf16* __restrict__ A, const __bf16* __restrict__ Bt, int K,
                               __bf16* __restrict__ q_b, __bf16* __restrict__ k_b,
                               __bf16* __restrict__ vt_b,
                               const float* __restrict__ bo_f, const int* __restrict__ flagp,
                               void* __restrict__ outp) {
  __shared__ __align__(16) __bf16 As[128 * 64];
  __shared__ __align__(16) __bf16 Bs[128 * 64];
  const int tid  = threadIdx.x;
  const int w    = tid >> 6, lane = tid & 63;
  const int quad = lane >> 4, lr = lane & 15;
  const int tm = blockIdx.y * 128, tn = blockIdx.x * 128;
  const int wm = (w >> 1) * 64, wn = (w & 1) * 64;
  const int lrow   = lane >> 3;
  const int gchunk = (lane & 7) ^ lrow;

  f32x4 acc[4][4] = {};

  for (int k0 = 0; k0 < K; k0 += 64) {
#pragma unroll
    for (int c = 0; c < 4; ++c) {
      const int chunk = w * 4 + c;             // wave-uniform LDS base
      const int row   = chunk * 8 + lrow;
      async_copy16(A  + (size_t)(tm + row) * K + k0 + gchunk * 8, As + chunk * 512);
      async_copy16(Bt + (size_t)(tn + row) * K + k0 + gchunk * 8, Bs + chunk * 512);
    }
    __syncthreads();   // drains vmcnt -> LDS image complete
#pragma unroll
    for (int ks = 0; ks < 2; ++ks) {
      bf16x8 af[4], bfr[4];
#pragma unroll
      for (int mi = 0; mi < 4; ++mi) {
        const int row = wm + mi * 16 + lr;
        const int ch  = (ks * 4 + quad) ^ (row & 7);
        af[mi] = *(const bf16x8*)(As + row * 64 + ch * 8);
      }
#pragma unroll
      for (int ni = 0; ni < 4; ++ni) {
        const int row = wn + ni * 16 + lr;
        const int ch  = (ks * 4 + quad) ^ (row & 7);
        bfr[ni] = *(const bf16x8*)(Bs + row * 64 + ch * 8);
      }
#pragma unroll
      for (int mi = 0; mi < 4; ++mi)
#pragma unroll
        for (int ni = 0; ni < 4; ++ni)
          acc[mi][ni] = __builtin_amdgcn_mfma_f32_16x16x32_bf16(af[mi], bfr[ni], acc[mi][ni], 0, 0, 0);
    }
    __syncthreads();   // all reads done before next iter's async writes
  }

  if (MODE == 0) {
#pragma unroll
    for (int mi = 0; mi < 4; ++mi) {
      const int mrow0 = tm + wm + mi * 16 + quad * 4;
      const int b  = mrow0 >> 11;
      const int t0 = mrow0 & 2047;
#pragma unroll
      for (int ni = 0; ni < 4; ++ni) {
        const int ncol = tn + wn + ni * 16 + lr;
        const int mat  = ncol >> 10;
        const int nn   = ncol & 1023;
        const int h = nn >> 6, hd = nn & 63;
        if (mat == 0) {
#pragma unroll
          for (int r = 0; r < 4; ++r)
            q_b[((size_t)((b * H_ + h) * T_ + t0 + r)) * HD_ + hd] =
                (__bf16)(acc[mi][ni][r] * 0.125f);
        } else if (mat == 1) {
#pragma unroll
          for (int r = 0; r < 4; ++r)
            k_b[((size_t)((b * H_ + h) * T_ + t0 + r)) * HD_ + hd] =
                (__bf16)(acc[mi][ni][r]);
        } else {
          bf16x4 pk;
#pragma unroll
          for (int r = 0; r < 4; ++r) pk[r] = (__bf16)(acc[mi][ni][r]);
          *(bf16x4*)(vt_b + ((size_t)(b * H_ + h) * HD_ + hd) * T_ + t0) = pk;
        }
      }
    }
  } else {
    const int f32out = *flagp;
#pragma unroll
    for (int mi = 0; mi < 4; ++mi) {
      const int m0 = tm + wm + mi * 16 + quad * 4;
#pragma unroll
      for (int ni = 0; ni < 4; ++ni) {
        const int n = tn + wn + ni * 16 + lr;
        const float bias = bo_f[n];
#pragma unroll
        for (int r = 0; r < 4; ++r) {
          const float val = acc[mi][ni][r] + bias;
          if (f32out) ((float*)outp)[(size_t)(m0 + r) * D_ + n] = val;
          else        ((__bf16*)outp)[(size_t)(m0 + r) * D_ + n] = (__bf16)val;
        }
      }
    }
  }
}

// ---------------------------------------------------------------------------
// Flash attention v3 (causal). Grid (16, B*H), block 256 = 4 waves.
// Block bx processes Q-tile pair (bx, 31-bx); BK_kv = 128 (two 64-tiles per
// softmax update -> halves shuffle-reductions/rescale/barriers per column).
// 128-col blocks per pair = floor(bx/2)+floor((31-bx)/2)+2 = 17, uniform.
// K[128][64] and V^T[64][128] staged once/block into XOR-swizzled LDS with
// register prefetch of block jb+1 overlapping compute of jb.
// sP single-buffered: explicit lgkmcnt(0) after pf reads kills the WAR.
// sP pitch 136 (68 words = 4 mod 32 -> 2-way bank access, free).
// ---------------------------------------------------------------------------
__launch_bounds__(256)
__global__ void attn_kernel(const __bf16* __restrict__ q_b, const __bf16* __restrict__ k_b,
                            const __bf16* __restrict__ vt_b, __bf16* __restrict__ ctx) {
  __shared__ __align__(16) __bf16 sK[128 * 64];      // [kv][hd], 8 16B-chunks/row
  __shared__ __align__(16) __bf16 sV[64 * 128];      // [hd][kv], 16 16B-chunks/row
  __shared__ __align__(16) __bf16 sP[4][16][136];    // per-wave P tile
  const int tid  = threadIdx.x;
  const int w    = tid >> 6, lane = tid & 63;
  const int quad = lane >> 4, lr = lane & 15;
  const int bh = blockIdx.y;
  const int bx = blockIdx.x;
  const __bf16* qh = q_b  + (size_t)bh * T_ * HD_;
  const __bf16* kh = k_b  + (size_t)bh * T_ * HD_;
  const __bf16* vh = vt_b + (size_t)bh * HD_ * T_;
  const int b = bh >> 4, h = bh & 15;

#pragma unroll
  for (int half = 0; half < 2; ++half) {
    const int tq = half ? (31 - bx) : bx;
    const int q0 = tq * 64 + w * 16;
    const int nt = tq / 2 + 1;    // 128-col blocks (last one causal-masked)

    bf16x8 qf[2];
#pragma unroll
    for (int ks = 0; ks < 2; ++ks)
      qf[ks] = *(const bf16x8*)(qh + (size_t)(q0 + lr) * HD_ + ks * 32 + quad * 8);

    f32x4 o[4] = {};
    float m_run[4], l_run[4];
#pragma unroll
    for (int r = 0; r < 4; ++r) { m_run[r] = -3.0e38f; l_run[r] = 0.f; }

    // prefetch block jb=0: 4 K-chunks + 4 V-chunks per thread
    bf16x8 kr[4], vr[4];
#pragma unroll
    for (int i = 0; i < 4; ++i) {
      const int id = i * 256 + tid;
      const int krow = id >> 3, kp = id & 7, kg = kp ^ (krow & 7);
      kr[i] = *(const bf16x8*)(kh + (size_t)krow * HD_ + kg * 8);
      const int vrow = id >> 4, vp = id & 15, vg = vp ^ (vrow & 15);
      vr[i] = *(const bf16x8*)(vh + (size_t)vrow * T_ + vg * 8);
    }

    for (int jb = 0; jb < nt; ++jb) {
      const int j0 = jb * 128;
      __syncthreads();   // all waves done reading sK/sV of previous block
#pragma unroll
      for (int i = 0; i < 4; ++i) {
        const int id = i * 256 + tid;
        const int krow = id >> 3, kp = id & 7;
        *(bf16x8*)(sK + krow * 64 + kp * 8) = kr[i];
        const int vrow = id >> 4, vp = id & 15;
        *(bf16x8*)(sV + vrow * 128 + vp * 8) = vr[i];
      }
      __syncthreads();
      if (jb + 1 < nt) {   // overlap next-block global loads with compute
        const int jn = j0 + 128;
#pragma unroll
        for (int i = 0; i < 4; ++i) {
          const int id = i * 256 + tid;
          const int krow = id >> 3, kp = id & 7, kg = kp ^ (krow & 7);
          kr[i] = *(const bf16x8*)(kh + (size_t)(jn + krow) * HD_ + kg * 8);
          const int vrow = id >> 4, vp = id & 15, vg = vp ^ (vrow & 15);
          vr[i] = *(const bf16x8*)(vh + (size_t)vrow * T_ + jn + vg * 8);
        }
      }
      // S = (Q/8) K^T for this wave's 16x128 stripe (K from LDS)
      f32x4 s[8] = {};
#pragma unroll
      for (int ni = 0; ni < 8; ++ni) {
        const int row = ni * 16 + lr;
#pragma unroll
        for (int ks = 0; ks < 2; ++ks) {
          const int ch = (ks * 4 + quad) ^ (row & 7);
          bf16x8 kf = *(const bf16x8*)(sK + row * 64 + ch * 8);
          s[ni] = __builtin_amdgcn_mfma_f32_16x16x32_bf16(qf[ks], kf, s[ni], 0, 0, 0);
        }
      }
      // causal mask (last 128-block only)
      if (j0 + 127 > q0) {
#pragma unroll
        for (int ni = 0; ni < 8; ++ni) {
          const int col = j0 + ni * 16 + lr;
#pragma unroll
          for (int r = 0; r < 4; ++r) {
            const int row = q0 + quad * 4 + r;
            if (col > row) s[ni][r] = -3.0e38f;
          }
        }
      }
      // online softmax over 128 cols (rows on the 16 lanes of each quad)
      float mt[4];
#pragma unroll
      for (int r = 0; r < 4; ++r) {
        float a0 = fmaxf(fmaxf(s[0][r], s[1][r]), fmaxf(s[2][r], s[3][r]));
        float a1 = fmaxf(fmaxf(s[4][r], s[5][r]), fmaxf(s[6][r], s[7][r]));
        mt[r] = fmaxf(a0, a1);
      }
#pragma unroll
      for (int off = 1; off <= 8; off <<= 1)
#pragma unroll
        for (int r = 0; r < 4; ++r)
          mt[r] = fmaxf(mt[r], __shfl_xor(mt[r], off, 16));
      float alpha[4], rs[4];
#pragma unroll
      for (int r = 0; r < 4; ++r) {
        const float mn = fmaxf(m_run[r], mt[r]);
        alpha[r] = __expf(m_run[r] - mn);
        m_run[r] = mn;
        float sum = 0.f;
#pragma unroll
        for (int ni = 0; ni < 8; ++ni) {
          const float pv = __expf(s[ni][r] - mn);
          s[ni][r] = pv;
          sum += pv;
        }
        rs[r] = sum;
      }
#pragma unroll
      for (int off = 1; off <= 8; off <<= 1)
#pragma unroll
        for (int r = 0; r < 4; ++r)
          rs[r] += __shfl_xor(rs[r], off, 16);
#pragma unroll
      for (int r = 0; r < 4; ++r)
        l_run[r] = l_run[r] * alpha[r] + rs[r];
#pragma unroll
      for (int ni = 0; ni < 4; ++ni)
#pragma unroll
        for (int r = 0; r < 4; ++r)
          o[ni][r] *= alpha[r];
      // P (C-layout) -> LDS -> A-layout fragments (per-wave region)
#pragma unroll
      for (int ni = 0; ni < 8; ++ni)
#pragma unroll
        for (int r = 0; r < 4; ++r)
          sP[w][quad * 4 + r][ni * 16 + lr] = (__bf16)s[ni][r];
      asm volatile("s_waitcnt lgkmcnt(0)" ::: "memory");
      bf16x8 pf[4];
#pragma unroll
      for (int ks = 0; ks < 4; ++ks)
        pf[ks] = *(const bf16x8*)(&sP[w][lr][ks * 32 + quad * 8]);
      asm volatile("s_waitcnt lgkmcnt(0)" ::: "memory");  // reads done -> next writes safe
      // O += P * V  (V^T from LDS: row = hd, cols = kv)
#pragma unroll
      for (int ni = 0; ni < 4; ++ni) {
        const int row = ni * 16 + lr;
#pragma unroll
        for (int ks = 0; ks < 4; ++ks) {
          const int ch = (ks * 4 + quad) ^ (row & 15);
          bf16x8 vf = *(const bf16x8*)(sV + row * 128 + ch * 8);
          o[ni] = __builtin_amdgcn_mfma_f32_16x16x32_bf16(pf[ks], vf, o[ni], 0, 0, 0);
        }
      }
    }
    // normalize and store ctx in merged [b*T+t][h*64+d] layout (bf16)
#pragma unroll
    for (int ni = 0; ni < 4; ++ni)
#pragma unroll
      for (int r = 0; r < 4; ++r) {
        const int t = q0 + quad * 4 + r;
        ctx[((size_t)(b * T_ + t)) * D_ + h * HD_ + ni * 16 + lr] =
            (__bf16)(o[ni][r] / l_run[r]);
      }
  }
}

// ---------------------------------------------------------------------------
extern "C" void kernel_launch(void* const* d_in, const int* in_sizes, int n_in,
                              void* d_out, int out_size, void* d_ws, size_t ws_size,
                              hipStream_t stream) {
  (void)in_sizes; (void)n_in; (void)out_size; (void)ws_size;
  const void* x  = d_in[0];
  const void* wq = d_in[1];
  const void* wk = d_in[2];
  const void* wv = d_in[3];
  const void* wo = d_in[4];
  const void* bo = d_in[5];

  char* ws = (char*)d_ws;
  __bf16* ctx    = (__bf16*)(ws + 0);           // [4096][1024] = 8 MB
  __bf16* wqkv_t = (__bf16*)(ws + 0);           // 3072x1024 = 6 MB (dead after gemm<0>)
  __bf16* wo_t   = (__bf16*)(ws + 8388608);     // 1024x1024 = 2 MB
  __bf16* q_b    = (__bf16*)(ws + 10485760);    // [2][16][2048][64] = 8 MB
  __bf16* k_b    = (__bf16*)(ws + 18874368);    // 8 MB
  __bf16* vt_b   = (__bf16*)(ws + 27262976);    // [2][16][64][2048] = 8 MB
  __bf16* xc     = (__bf16*)(ws + 35651584);    // canonical bf16 x = 8 MB
  float*  bo_f   = (float*) (ws + 44040192);    // 4 KB
  int*    flagp  = (int*)   (ws + 44044288);    // 4 B

  detect_kernel<<<1, 256, 0, stream>>>(x, bo, flagp, bo_f);
  convert_x_kernel<<<4096, 256, 0, stream>>>(x, flagp, xc);
  transpose_w_kernel<<<dim3(32, 32, 4), dim3(32, 8, 1), 0, stream>>>(wq, wk, wv, wo, flagp, wqkv_t, wo_t);
  gemm128_kernel<0><<<dim3(24, 32), 256, 0, stream>>>(xc, wqkv_t, 1024, q_b, k_b, vt_b, nullptr, flagp, nullptr);
  attn_kernel<<<dim3(16, 32), 256, 0, stream>>>(q_b, k_b, vt_b, ctx);
  gemm128_kernel<1><<<dim3(8, 32), 256, 0, stream>>>(ctx, wo_t, 1024, nullptr, nullptr, nullptr, bo_f, flagp, d_out);
}